// Round 7
// baseline (288.306 us; speedup 1.0000x reference)
//
#include <hip/hip_runtime.h>

#define B 4
#define N 2048
#define V 12
#define C 50
#define P 16384      // 128*128 = 2^14
#define PQ 4096      // P/4 pixel-quads per image
#define PSTRIDE 56   // floats per pool entry: 50 exps + sum + pad (224 B, 16B-aligned)

// ---------------------------------------------------------------------------
// Fused single pass, ARRAY-FREE (no spill):
//  Phase 1: float4 coalesced stream, RUNNING argmax only (~30 VGPR live).
//  Phase 2: candidate pixels (~7%) re-read their 50 logits from pred --
//           those lines were just streamed, so they are Infinity-Cache
//           resident (157 MB < 256 MB L3; zero extra HBM traffic).
//           exp+sum -> pool[bv*P+p] via 13 float4 stores; atomicMax the
//           reference's exact key = argmax*P + p into winner[b,v,n].
// ---------------------------------------------------------------------------
__global__ __launch_bounds__(256) void k1_fused(
    const float4* __restrict__ predv,    // (B*V, C, PQ)
    const float*  __restrict__ pred,     // (B*V, C, P) same memory
    const int4*   __restrict__ p2pv,     // (B*V, PQ)
    const int*    __restrict__ parts_nb, // (B,)
    int*          __restrict__ winner,   // (B*V*N), init -1
    float*        __restrict__ pool) {   // (B*V*P, PSTRIDE)
  int t = blockIdx.x * 256 + threadIdx.x;   // grid exact: B*V*PQ threads
  int q  = t & (PQ - 1);
  int bv = t >> 12;
  int b  = bv / V;

  // ---- phase 1: running argmax over C, 4 pixels, no arrays ----
  size_t base = (size_t)bv * C * PQ + q;
  float4 x = predv[base];
  float m0 = x.x, m1 = x.y, m2 = x.z, m3 = x.w;
  int   a0 = 0,  a1 = 0,  a2 = 0,  a3 = 0;
  for (int c = 1; c < C; ++c) {
    float4 y = predv[base + (size_t)c * PQ];
    if (y.x > m0) { m0 = y.x; a0 = c; }
    if (y.y > m1) { m1 = y.y; a1 = c; }
    if (y.z > m2) { m2 = y.z; a2 = c; }
    if (y.w > m3) { m3 = y.w; a3 = c; }
  }

  int4 pt = p2pv[(size_t)bv * PQ + q];
  int pn = parts_nb[b];
  int p0 = q * 4;

  // ---- phase 2: per candidate pixel, L3-hit re-read + exp + pool write ----
  #pragma unroll
  for (int j = 0; j < 4; ++j) {
    int ptj = (j == 0) ? pt.x : (j == 1) ? pt.y : (j == 2) ? pt.z : pt.w;
    int aj  = (j == 0) ? a0   : (j == 1) ? a1   : (j == 2) ? a2   : a3;
    int p   = p0 + j;
    if (ptj != -1 && aj >= 1 && aj <= pn) {
      const float* pp = pred + (size_t)bv * C * P + p;
      float* dst = pool + (size_t)(bv * P + p) * PSTRIDE;
      float s = 0.f;
      #pragma unroll
      for (int c4 = 0; c4 < 12; ++c4) {
        float4 e4;
        e4.x = __expf(pp[(size_t)(4 * c4 + 0) * P]);
        e4.y = __expf(pp[(size_t)(4 * c4 + 1) * P]);
        e4.z = __expf(pp[(size_t)(4 * c4 + 2) * P]);
        e4.w = __expf(pp[(size_t)(4 * c4 + 3) * P]);
        s += (e4.x + e4.y) + (e4.z + e4.w);
        ((float4*)dst)[c4] = e4;
      }
      float e48 = __expf(pp[(size_t)48 * P]);
      float e49 = __expf(pp[(size_t)49 * P]);
      s += e48 + e49;
      dst[48] = e48;
      dst[49] = e49;
      dst[C]  = s;
      atomicMax(&winner[bv * N + ptj], aj * P + p);   // reference's exact key
    }
  }
}

// ---------------------------------------------------------------------------
// Reduce: one wave per (b,n). key & (P-1) is the winning pixel -> pool slot.
// Lanes 0..49 read the 224 B entry contiguously (L2/L3-hot). Average valid
// views with vw/sumexp weights; cnt=0 -> divide by 1 (output 0).
// ---------------------------------------------------------------------------
__global__ __launch_bounds__(256) void k3_reduce(
    const int*   __restrict__ winner,   // (B*V*N)
    const float* __restrict__ pool,     // (B*V*P, PSTRIDE)
    const float* __restrict__ vw,       // (B*V,)
    float*       __restrict__ out) {    // (B, C, N)
  int wid  = blockIdx.x * 4 + (threadIdx.x >> 6);
  int lane = threadIdx.x & 63;
  int b = wid >> 11;                    // N = 2048
  int n = wid & (N - 1);

  float acc = 0.f;
  int cnt = 0;
  #pragma unroll
  for (int v = 0; v < V; ++v) {
    int bv  = b * V + v;
    int key = winner[bv * N + n];       // wave-uniform -> scalar broadcast
    bool valid = key >= 0;
    int wp = key & (P - 1);
    const float* src = pool + (size_t)(bv * P + wp) * PSTRIDE;
    float e = (valid && lane < C) ? src[lane] : 0.f;
    float s = valid ? src[C] : 1.f;
    float f = valid ? (vw[bv] / s) : 0.f;
    cnt += valid ? 1 : 0;
    acc += e * f;
  }
  if (lane < C)
    out[((size_t)b * C + lane) * N + n] = acc / (float)(cnt > 0 ? cnt : 1);
}

extern "C" void kernel_launch(void* const* d_in, const int* in_sizes, int n_in,
                              void* d_out, int out_size, void* d_ws, size_t ws_size,
                              hipStream_t stream) {
  const float* pred  = (const float*)d_in[1];
  const int*   p2p   = (const int*)d_in[2];
  const float* vw    = (const float*)d_in[3];
  const int*   parts = (const int*)d_in[4];
  float* out = (float*)d_out;

  char* ws = (char*)d_ws;
  int*   winner = (int*)ws;                                  // 384 KiB
  float* pool   = (float*)(ws + (size_t)B * V * N * sizeof(int) + 128); // 176 MiB max

  hipMemsetAsync(winner, 0xFF, (size_t)B * V * N * sizeof(int), stream); // -1 fill

  int nthreads = B * V * PQ;                                 // 196608
  k1_fused<<<nthreads / 256, 256, 0, stream>>>(
      (const float4*)pred, pred, (const int4*)p2p, parts, winner, pool);

  k3_reduce<<<(B * N) / 4, 256, 0, stream>>>(winner, pool, vw, out);
}